// Round 9
// baseline (235.012 us; speedup 1.0000x reference)
//
#include <hip/hip_runtime.h>
#include <hip/hip_bf16.h>
#include <cstdint>
#include <cstddef>

// Problem constants (B,N,M,C2,C1) = (4, 8192, 2048, 256, 128)
static constexpr int BB   = 4;
static constexpr int NN   = 8192;
static constexpr int MM   = 2048;
static constexpr int C1   = 128;
static constexpr int C2   = 256;
static constexpr int CH0  = C2 + C1;   // 384  (K of GEMM0)
static constexpr int O0   = 256;       // out channels layer 0
static constexpr int O1   = 128;       // out channels layer 1
static constexpr int NCOL = BB * NN;   // 32768 columns
static constexpr float BN_EPS = 1e-5f;

using u16 = unsigned short;
typedef __attribute__((ext_vector_type(8))) short short8;
typedef __attribute__((ext_vector_type(4))) float f32x4;

static __device__ __forceinline__ float bf2f(u16 u) {
    union { unsigned int i; float f; } v; v.i = ((unsigned int)u) << 16; return v.f;
}
static __device__ __forceinline__ u16 f2bf(float f) {
    union { float f; unsigned int i; } v; v.f = f;
    unsigned int r = (v.i + 0x7fffu + ((v.i >> 16) & 1u)) >> 16;
    return (u16)r;
}

// ---------------------------------------------------------------------------
// K1: f32 -> bf16 batched transpose  in[b][R][C] (f32) -> out[b][C][R] (bf16)
__global__ __launch_bounds__(256) void transpose_f32_bf16(const float* __restrict__ in,
                                                          u16* __restrict__ out,
                                                          int R, int C) {
    __shared__ float tile[32][33];
    int b  = blockIdx.z;
    int c0 = blockIdx.x * 32;
    int r0 = blockIdx.y * 32;
    const float* pin = in  + (size_t)b * R * C;
    u16*        pout = out + (size_t)b * R * C;
    int tx = threadIdx.x, ty = threadIdx.y;   // block (32,8)
#pragma unroll
    for (int j = 0; j < 4; ++j) {
        int r = ty + j * 8;
        tile[r][tx] = pin[(size_t)(r0 + r) * C + (c0 + tx)];
    }
    __syncthreads();
#pragma unroll
    for (int j = 0; j < 4; ++j) {
        int c = ty + j * 8;
        pout[(size_t)(c0 + c) * R + (r0 + tx)] = f2bf(tile[tx][c]);
    }
}

// ---------------------------------------------------------------------------
// elementwise f32 -> bf16 cast of BOTH weight tensors in one launch
__global__ __launch_bounds__(256) void cast2_f32_bf16(const float* __restrict__ a,
                                                      u16* __restrict__ oa, int na,
                                                      const float* __restrict__ b,
                                                      u16* __restrict__ ob, int nb) {
    int i = blockIdx.x * 256 + threadIdx.x;
    if (i < na) oa[i] = f2bf(a[i]);
    else if (i < na + nb) ob[i - na] = f2bf(b[i - na]);
}

// ---------------------------------------------------------------------------
// K2: 3-NN + combined (distance * normal) interpolation weights. f32 inputs.
// VALU-bound at ~70% issue (r8 analysis): ~20 inst/point for contract-off
// distance + sorted top-3 insert with exact top_k tie semantics. Near-floor.
__global__ __launch_bounds__(256) void three_nn_kernel(const float* __restrict__ xyz1,
                                                       const float* __restrict__ xyz2,
                                                       const float* __restrict__ norm1,
                                                       const float* __restrict__ norm2,
                                                       int* __restrict__ idxOut,
                                                       float* __restrict__ wOut) {
#pragma clang fp contract(off)
    constexpr int CH = 1024;             // points per LDS chunk
    __shared__ float4 pts[CH];
    int b    = blockIdx.x >> 8;          // 256 blocks of 32 queries per batch
    int nblk = blockIdx.x & 255;
    int t    = threadIdx.x;
    int j    = t & 7;                    // lane within the 8-thread query group

    int n = nblk * 32 + (t >> 3);
    const float* x1 = xyz1 + (size_t)b * 3 * NN;
    float qx = x1[n], qy = x1[NN + n], qz = x1[2 * NN + n];
    float qq = (qx * qx + qy * qy) + qz * qz;

    const float* x2 = xyz2 + (size_t)b * 3 * MM;

    float d0 = 3.4e38f, d1 = 3.4e38f, d2v = 3.4e38f;
    int   i0 = 0, i1 = 0, i2 = 0;

    for (int chunk = 0; chunk < MM / CH; ++chunk) {
        __syncthreads();                 // prior scan done before overwrite
        for (int i = t; i < CH; i += 256) {
            int m = chunk * CH + i;
            float px = x2[m];
            float py = x2[MM + m];
            float pz = x2[2 * MM + m];
            float pp = (px * px + py * py) + pz * pz;
            pts[i] = make_float4(px, py, pz, pp);
        }
        __syncthreads();

#pragma unroll 8
        for (int s = 0; s < CH / 8; ++s) {
            int ml = s * 8 + j;          // ascending per thread -> stable ties
            float4 P = pts[ml];
            float qp = (qx * P.x + qy * P.y) + qz * P.z;
            float d  = (qq + P.w) - 2.0f * qp;
            if (d < d2v) {
                int m = chunk * CH + ml;
                if (d < d1) {
                    if (d < d0) { d2v = d1; i2 = i1; d1 = d0; i1 = i0; d0 = d; i0 = m; }
                    else        { d2v = d1; i2 = i1; d1 = d;  i1 = m; }
                } else          { d2v = d;  i2 = m; }
            }
        }
    }

    // merge sorted triples across the 8 lanes of the group (lexicographic tie-break)
#pragma unroll
    for (int k = 1; k <= 4; k <<= 1) {
        float e0 = __shfl_xor(d0, k, 64), e1 = __shfl_xor(d1, k, 64), e2 = __shfl_xor(d2v, k, 64);
        int   f0 = __shfl_xor(i0, k, 64), f1 = __shfl_xor(i1, k, 64), f2 = __shfl_xor(i2, k, 64);
        float ed[3] = {e0, e1, e2}; int ef[3] = {f0, f1, f2};
#pragma unroll
        for (int e = 0; e < 3; ++e) {
            float dd = ed[e]; int ff = ef[e];
            bool b2 = (dd < d2v) || (dd == d2v && ff < i2);
            if (b2) {
                bool b1 = (dd < d1) || (dd == d1 && ff < i1);
                if (b1) {
                    d2v = d1; i2 = i1;
                    bool b0 = (dd < d0) || (dd == d0 && ff < i0);
                    if (b0) { d1 = d0; i1 = i0; d0 = dd; i0 = ff; }
                    else    { d1 = dd; i1 = ff; }
                } else { d2v = dd; i2 = ff; }
            }
        }
    }

    if (j == 0) {
        float s0 = sqrtf(fmaxf(d0, 1e-20f));
        float s1 = sqrtf(fmaxf(d1, 1e-20f));
        float s2 = sqrtf(fmaxf(d2v, 1e-20f));
        float r0 = 1.0f / fmaxf(s0, 1e-10f);
        float r1 = 1.0f / fmaxf(s1, 1e-10f);
        float r2 = 1.0f / fmaxf(s2, 1e-10f);
        float rs = (r0 + r1) + r2;
        float w0 = r0 / rs, w1 = r1 / rs, w2 = r2 / rs;

        const float* nm1 = norm1 + (size_t)b * 3 * NN;
        const float* nm2 = norm2 + (size_t)b * 3 * MM;
        float ax = nm1[n], ay = nm1[NN + n], az = nm1[2 * NN + n];
        float nd[3]; int ii[3] = {i0, i1, i2};
#pragma unroll
        for (int k = 0; k < 3; ++k) {
            int ik = ii[k];
            float dx = ax - nm2[ik];
            float dy = ay - nm2[MM + ik];
            float dz = az - nm2[2 * MM + ik];
            nd[k] = sqrtf((dx * dx + dy * dy) + dz * dz);
        }
        float m0 = 1.0f / fmaxf(nd[0], 1e-10f);
        float m1 = 1.0f / fmaxf(nd[1], 1e-10f);
        float m2 = 1.0f / fmaxf(nd[2], 1e-10f);
        float ms = (m0 + m1) + m2;

        int col = b * NN + n;
        idxOut[col * 3 + 0] = i0;
        idxOut[col * 3 + 1] = i1;
        idxOut[col * 3 + 2] = i2;
        wOut[col * 3 + 0] = w0 * (m0 / ms);
        wOut[col * 3 + 1] = w1 * (m1 / ms);
        wOut[col * 3 + 2] = w2 * (m2 / ms);
    }
}

// ---------------------------------------------------------------------------
// K3: build x^T[col][k] (bf16, K-contiguous). One wave per column.
__global__ __launch_bounds__(256) void build_xT_kernel(const int* __restrict__ idx,
                                                       const float* __restrict__ w,
                                                       const u16* __restrict__ p2T,
                                                       const u16* __restrict__ p1T,
                                                       u16* __restrict__ xT) {
    int t  = threadIdx.x;
    int l  = t & 63;
    int wv = t >> 6;
    int col = blockIdx.x * 4 + wv;
    int b = col >> 13;
    int n = col & (NN - 1);
    int i0 = idx[col * 3 + 0], i1 = idx[col * 3 + 1], i2 = idx[col * 3 + 2];
    float w0 = w[col * 3 + 0], w1 = w[col * 3 + 1], w2 = w[col * 3 + 2];
    const u16* base = p2T + (size_t)b * MM * C2;

    union { uint2 v; u16 u[4]; } a0, a1, a2, o;
    a0.v = *(const uint2*)(base + (size_t)i0 * C2 + l * 4);
    a1.v = *(const uint2*)(base + (size_t)i1 * C2 + l * 4);
    a2.v = *(const uint2*)(base + (size_t)i2 * C2 + l * 4);
#pragma unroll
    for (int e = 0; e < 4; ++e)
        o.u[e] = f2bf(w0 * bf2f(a0.u[e]) + w1 * bf2f(a1.u[e]) + w2 * bf2f(a2.u[e]));
    *(uint2*)(xT + (size_t)col * CH0 + l * 4) = o.v;

    if (l < 32) {  // points1 channels 0..127
        uint2 p = *(const uint2*)(p1T + ((size_t)b * NN + n) * C1 + l * 4);
        *(uint2*)(xT + (size_t)col * CH0 + C2 + l * 4) = p;
    }
}

// ---------------------------------------------------------------------------
// K4/K6: GEMM  C^T[col][m] = sum_k A[m][k] * Bt[col][k] + bias[m]
// 128 rows x COLT cols, BK=64, 256 threads, 16x16x32 bf16 MFMA.
// A staging: async global_load_lds (16B/lane), XOR-swizzled, double-buffered.
// B staging: DMA if !FUSEB; if FUSEB, VGPR path applying relu(f*sc+sh) with
// sc/sh pre-loaded in LDS (fused BN+ReLU of the previous layer).
// BN stats: shuffle-reduce -> LDS atomics -> one plain partial record/block.
// C-store: through LDS tile -> coalesced uint4 stores.
template <int KDIM, int LDC, int COLT, bool FUSEB>
__global__ __launch_bounds__(256) void gemm_bt_kernel(const u16* __restrict__ A,
                                                      const u16* __restrict__ Bt,
                                                      u16* __restrict__ Ct,
                                                      const float* __restrict__ bias,
                                                      const float* __restrict__ scaleB,
                                                      const float* __restrict__ shiftB,
                                                      float* __restrict__ partials) {
    constexpr int KT  = KDIM / 64;
    constexpr int NI  = COLT / 32;
    constexpr int ASZ = 128 * 64;            // u16 elements per A buffer
    constexpr int BSZ = COLT * 64;
    // staging (overlaid by Cs+reds after loop) + optional scale/shift cache
    __shared__ u16 smem[2 * ASZ + 2 * BSZ];
    __shared__ float sSc[FUSEB ? KDIM : 1];
    __shared__ float sSh[FUSEB ? KDIM : 1];

    int t   = threadIdx.x;
    int l   = t & 63;
    int wv  = t >> 6;
    int rl  = l >> 3;                    // staging row-in-group 0..7
    int cg  = ((l & 7) ^ rl) * 8;        // swizzled global chunk (elements)
    int mb0 = blockIdx.y * 128;
    int cb0 = blockIdx.x * COLT;
    int lm  = l & 15;
    int q   = l >> 4;
    int wm0 = (wv & 1) * 64;
    int wn0 = (wv >> 1) * (COLT / 2);

    const u16* Abase = A  + (size_t)mb0 * KDIM;
    const u16* Bbase = Bt + (size_t)cb0 * KDIM;

    if (FUSEB) {
        for (int i = t; i < KDIM; i += 256) { sSc[i] = scaleB[i]; sSh[i] = shiftB[i]; }
        __syncthreads();
    }

    auto stage = [&](int buf, int k0) {
#pragma unroll
        for (int iss = 0; iss < 4; ++iss) {              // A: 128 rows, DMA
            int row = wv * 32 + iss * 8;
            const u16* g = Abase + (size_t)(row + rl) * KDIM + k0 + cg;
            __builtin_amdgcn_global_load_lds(
                (const __attribute__((address_space(1))) unsigned int*)g,
                (__attribute__((address_space(3))) unsigned int*)(&smem[buf * ASZ + row * 64]),
                16, 0, 0);
        }
        if (!FUSEB) {
#pragma unroll
            for (int iss = 0; iss < COLT / 32; ++iss) {  // B: COLT rows, DMA
                int row = wv * (COLT / 4) + iss * 8;
                const u16* g = Bbase + (size_t)(row + rl) * KDIM + k0 + cg;
                __builtin_amdgcn_global_load_lds(
                    (const __attribute__((address_space(1))) unsigned int*)g,
                    (__attribute__((address_space(3))) unsigned int*)(&smem[2 * ASZ + buf * BSZ + row * 64]),
                    16, 0, 0);
            }
        } else {
            // VGPR path with fused BN+ReLU: COLT*64 elems / 256 thr = 16/thread
            constexpr int EPT = (COLT * 64) / (256 * 16);  // row-groups (1 for COLT=64)
#pragma unroll
            for (int g8 = 0; g8 < EPT; ++g8) {
                int row = g8 * 64 + (t >> 2);            // 0..COLT-1
                int kc  = (t & 3) * 16;
                const u16* gp = Bbase + (size_t)row * KDIM + k0 + kc;
                union { uint4 v; u16 u[8]; } lo, hi;
                lo.v = *(const uint4*)gp;
                hi.v = *(const uint4*)(gp + 8);
#pragma unroll
                for (int e = 0; e < 8; ++e) {
                    float f0 = bf2f(lo.u[e]);
                    lo.u[e] = f2bf(fmaxf(f0 * sSc[k0 + kc + e] + sSh[k0 + kc + e], 0.f));
                    float f1 = bf2f(hi.u[e]);
                    hi.u[e] = f2bf(fmaxf(f1 * sSc[k0 + kc + 8 + e] + sSh[k0 + kc + 8 + e], 0.f));
                }
                int c0 = kc >> 3;                        // chunk index of lo
                u16* dstB = &smem[2 * ASZ + buf * BSZ + row * 64];
                *(uint4*)&dstB[((c0)     ^ (row & 7)) * 8] = lo.v;
                *(uint4*)&dstB[((c0 + 1) ^ (row & 7)) * 8] = hi.v;
            }
        }
    };

    f32x4 acc[4][NI] = {};

    stage(0, 0);
    for (int kt = 0; kt < KT; ++kt) {
        __syncthreads();                                  // drains DMA + ds_writes
        if (kt + 1 < KT) stage((kt + 1) & 1, (kt + 1) * 64);
        const u16* As = &smem[(kt & 1) * ASZ];
        const u16* Bs = &smem[2 * ASZ + (kt & 1) * BSZ];
#pragma unroll
        for (int ks = 0; ks < 2; ++ks) {
            int csw = ((ks * 4 + q) ^ (lm & 7)) * 8;      // un-swizzle chunk offset
            short8 av[4], bv[NI];
#pragma unroll
            for (int mi = 0; mi < 4; ++mi)
                av[mi] = *(const short8*)&As[(wm0 + mi * 16 + lm) * 64 + csw];
#pragma unroll
            for (int ni = 0; ni < NI; ++ni)
                bv[ni] = *(const short8*)&Bs[(wn0 + ni * 16 + lm) * 64 + csw];
#pragma unroll
            for (int mi = 0; mi < 4; ++mi)
#pragma unroll
                for (int ni = 0; ni < NI; ++ni)
                    acc[mi][ni] = __builtin_amdgcn_mfma_f32_16x16x32_bf16(
                        av[mi], bv[ni], acc[mi][ni], 0, 0, 0);
        }
    }

    // ---- Epilogue (LDS overlay): Cs = COLT x 136 u16, reds = 256 floats ----
    u16*   Cs   = smem;                              // [colL*136 + m]
    float* reds = (float*)&smem[COLT * 136];         // [s*128 + chL]

    __syncthreads();                                  // all MFMA LDS reads done
    if (t < 256) reds[t] = 0.f;
    __syncthreads();

#pragma unroll
    for (int mi = 0; mi < 4; ++mi) {
        int chL = wm0 + mi * 16 + q * 4;             // local channel, 4 consecutive
        float bv4[4];
#pragma unroll
        for (int r = 0; r < 4; ++r) bv4[r] = bias[mb0 + chL + r];
        float s[4]  = {0.f, 0.f, 0.f, 0.f};
        float s2[4] = {0.f, 0.f, 0.f, 0.f};
#pragma unroll
        for (int ni = 0; ni < NI; ++ni) {
            int colL = wn0 + ni * 16 + lm;
            union { u16 u[4]; uint2 d; } pk;
#pragma unroll
            for (int r = 0; r < 4; ++r) {
                float v = acc[mi][ni][r] + bv4[r];
                s[r]  += v;
                s2[r] += v * v;
                pk.u[r] = f2bf(v);
            }
            *(uint2*)&Cs[colL * 136 + chL] = pk.d;
        }
#pragma unroll
        for (int r = 0; r < 4; ++r) {
            float a = s[r], b2 = s2[r];
#pragma unroll
            for (int off = 1; off < 16; off <<= 1) {
                a  += __shfl_xor(a, off, 64);
                b2 += __shfl_xor(b2, off, 64);
            }
            if (lm == 0) {
                atomicAdd(&reds[chL + r], a);          // LDS atomic (on-CU)
                atomicAdd(&reds[128 + chL + r], b2);
            }
        }
    }
    __syncthreads();

    // coalesced C-store: COLT rows x 128 m; each half-row = 64 u16 = 8 x uint4
    for (int u = t; u < COLT * 2; u += 256) {
        int c = u >> 1, h = u & 1;
        const u16* src = &Cs[c * 136 + h * 64];
        u16* dst = Ct + (size_t)(cb0 + c) * LDC + mb0 + h * 64;
#pragma unroll
        for (int jj = 0; jj < 8; ++jj)
            *(uint4*)(dst + jj * 8) = *(const uint4*)(src + jj * 8);
    }
    // one plain partial record per block
    partials[((size_t)blockIdx.y * gridDim.x + blockIdx.x) * 256 + t] = reds[t];
}

// ---------------------------------------------------------------------------
// K5a: stage-1 partial reduction: 16 blocks, block r sums `chunk` records.
__global__ __launch_bounds__(256) void reduce_partials_kernel(const float* __restrict__ in,
                                                              float* __restrict__ out,
                                                              int chunk) {
    int t = threadIdx.x, r = blockIdx.x;
    const float* base = in + (size_t)r * chunk * 256;
    float s = 0.f;
    for (int i = 0; i < chunk; ++i) s += base[(size_t)i * 256 + t];
    out[(size_t)r * 256 + t] = s;
}

// ---------------------------------------------------------------------------
// K5b: fold reduced stats into scale/shift. halfStride = records per y-half.
__global__ void bn_params_kernel(const float* __restrict__ red, int nbx, int halfStride,
                                 const float* __restrict__ g,
                                 const float* __restrict__ be,
                                 float* __restrict__ scale,
                                 float* __restrict__ shift,
                                 int Mtot, float invN) {
    int c = threadIdx.x;
    if (c >= Mtot) return;
    int by = c >> 7, chL = c & 127;
    const float* base = red + (size_t)by * halfStride * 256;
    float s = 0.f, s2 = 0.f;
    for (int i = 0; i < nbx; ++i) {
        s  += base[(size_t)i * 256 + chL];
        s2 += base[(size_t)i * 256 + 128 + chL];
    }
    float mean = s * invN;
    float var  = fmaxf(s2 * invN - mean * mean, 0.f);
    float inv  = rsqrtf(var + BN_EPS);
    float sc   = g[c] * inv;
    scale[c] = sc;
    shift[c] = be[c] - mean * sc;
}

// ---------------------------------------------------------------------------
// K8: final BN+ReLU on y1^T[col][c] (bf16) and transpose to out[b][c][n] (f32).
__global__ __launch_bounds__(256) void finalize_kernel(const u16* __restrict__ y1T,
                                                       const float* __restrict__ scale,
                                                       const float* __restrict__ shift,
                                                       float* __restrict__ out) {
    __shared__ float tile[64][129];
    int t  = threadIdx.x;
    int b  = blockIdx.y;
    int n0 = blockIdx.x * 64;
#pragma unroll
    for (int it = 0; it < 32; ++it) {
        int flat = it * 256 + t;
        int cl = flat >> 7;          // local col 0..63
        int c  = flat & 127;
        int col = b * NN + n0 + cl;
        float v = bf2f(y1T[(size_t)col * O1 + c]);
        tile[cl][c] = fmaxf(v * scale[c] + shift[c], 0.f);
    }
    __syncthreads();
#pragma unroll
    for (int it = 0; it < 32; ++it) {
        int flat = it * 256 + t;
        int c  = flat >> 6;          // channel 0..127
        int nl = flat & 63;
        out[(size_t)b * O1 * NN + (size_t)c * NN + n0 + nl] = tile[nl][c];
    }
}

// ---------------------------------------------------------------------------
extern "C" void kernel_launch(void* const* d_in, const int* in_sizes, int n_in,
                              void* d_out, int out_size, void* d_ws, size_t ws_size,
                              hipStream_t stream) {
    (void)in_sizes; (void)n_in; (void)out_size; (void)ws_size;

    const float* xyz1    = (const float*)d_in[0];
    const float* xyz2    = (const float*)d_in[1];
    const float* norm1   = (const float*)d_in[2];
    const float* norm2   = (const float*)d_in[3];
    const float* points1 = (const float*)d_in[4];
    const float* points2 = (const float*)d_in[5];
    const float* W0f     = (const float*)d_in[6];
    const float* b0      = (const float*)d_in[7];
    const float* g0      = (const float*)d_in[8];
    const float* be0     = (const float*)d_in[9];
    const float* W1f     = (const float*)d_in[10];
    const float* b1      = (const float*)d_in[11];
    const float* g1      = (const float*)d_in[12];
    const float* be1     = (const float*)d_in[13];
    float* out = (float*)d_out;

    // workspace carve-up (all 256B-aligned)
    char* w8 = (char*)d_ws;
    size_t off = 0;
    auto carve = [&](size_t bytes) { void* p = w8 + off; off += (bytes + 255) & ~(size_t)255; return p; };
    int*   idxW   = (int*)  carve((size_t)NCOL * 3 * sizeof(int));
    float* wW     = (float*)carve((size_t)NCOL * 3 * sizeof(float));
    u16*   p2T    = (u16*)  carve((size_t)BB * MM * C2 * 2);
    u16*   p1T    = (u16*)  carve((size_t)BB * NN * C1 * 2);
    u16*   W0b    = (u16*)  carve((size_t)O0 * CH0 * 2);
    u16*   W1b    = (u16*)  carve((size_t)O1 * O0 * 2);
    u16*   xT     = (u16*)  carve((size_t)NCOL * CH0 * 2);
    u16*   y0T    = (u16*)  carve((size_t)NCOL * O0 * 2);
    u16*   y1T    = (u16*)  carve((size_t)NCOL * O1 * 2);
    float* part0  = (float*)carve((size_t)1024 * 256 * sizeof(float)); // 1024 records
    float* part1  = (float*)carve((size_t)512 * 256 * sizeof(float));  // 512 records
    float* red0   = (float*)carve((size_t)16 * 256 * sizeof(float));
    float* red1   = (float*)carve((size_t)16 * 256 * sizeof(float));
    float* scale0 = (float*)carve(O0 * sizeof(float));
    float* shift0 = (float*)carve(O0 * sizeof(float));
    float* scale1 = (float*)carve(O1 * sizeof(float));
    float* shift1 = (float*)carve(O1 * sizeof(float));

    const float invN = 1.0f / (float)NCOL;

    transpose_f32_bf16<<<dim3(MM / 32, C2 / 32, BB), dim3(32, 8), 0, stream>>>(points2, p2T, C2, MM);
    transpose_f32_bf16<<<dim3(NN / 32, C1 / 32, BB), dim3(32, 8), 0, stream>>>(points1, p1T, C1, NN);
    cast2_f32_bf16<<<(O0 * CH0 + O1 * O0 + 255) / 256, 256, 0, stream>>>(
        W0f, W0b, O0 * CH0, W1f, W1b, O1 * O0);

    three_nn_kernel<<<BB * (NN / 32), 256, 0, stream>>>(xyz1, xyz2, norm1, norm2, idxW, wW);

    build_xT_kernel<<<NCOL / 4, 256, 0, stream>>>(idxW, wW, p2T, p1T, xT);

    // GEMM0: 512 x-blocks x 2 y-halves = 1024 blocks (4/CU), COLT=64
    gemm_bt_kernel<CH0, O0, 64, false><<<dim3(NCOL / 64, O0 / 128), 256, 0, stream>>>(
        W0b, xT, y0T, b0, nullptr, nullptr, part0);
    // stats: 1024 records -> 16 (8 per y-half) -> scale/shift
    reduce_partials_kernel<<<16, 256, 0, stream>>>(part0, red0, 64);
    bn_params_kernel<<<1, O0, 0, stream>>>(red0, 8, 8, g0, be0, scale0, shift0, O0, invN);

    // GEMM1 with fused BN+ReLU on B (y0 raw -> z0 on the fly)
    gemm_bt_kernel<O0, O1, 64, true><<<dim3(NCOL / 64, O1 / 128), 256, 0, stream>>>(
        W1b, y0T, y1T, b1, scale0, shift0, part1);
    reduce_partials_kernel<<<16, 256, 0, stream>>>(part1, red1, 32);
    bn_params_kernel<<<1, O1, 0, stream>>>(red1, 16, 0, g1, be1, scale1, shift1, O1, invN);

    finalize_kernel<<<dim3(NN / 64, BB), 256, 0, stream>>>(y1T, scale1, shift1, out);
}

// Round 10
// 205.656 us; speedup vs baseline: 1.1427x; 1.1427x over previous
//
#include <hip/hip_runtime.h>
#include <hip/hip_bf16.h>
#include <cstdint>
#include <cstddef>

// Problem constants (B,N,M,C2,C1) = (4, 8192, 2048, 256, 128)
static constexpr int BB   = 4;
static constexpr int NN   = 8192;
static constexpr int MM   = 2048;
static constexpr int C1   = 128;
static constexpr int C2   = 256;
static constexpr int CH0  = C2 + C1;   // 384  (K of GEMM0)
static constexpr int O0   = 256;       // out channels layer 0
static constexpr int O1   = 128;       // out channels layer 1
static constexpr int NCOL = BB * NN;   // 32768 columns
static constexpr float BN_EPS = 1e-5f;

using u16 = unsigned short;
typedef __attribute__((ext_vector_type(8))) short short8;
typedef __attribute__((ext_vector_type(4))) float f32x4;

static __device__ __forceinline__ float bf2f(u16 u) {
    union { unsigned int i; float f; } v; v.i = ((unsigned int)u) << 16; return v.f;
}
static __device__ __forceinline__ u16 f2bf(float f) {
    union { float f; unsigned int i; } v; v.f = f;
    unsigned int r = (v.i + 0x7fffu + ((v.i >> 16) & 1u)) >> 16;
    return (u16)r;
}

// ---------------------------------------------------------------------------
// K1 (merged prep): blocks 0..2047 transpose points2 (256x2048 -> 2048x256),
// blocks 2048..6143 transpose points1 (128x8192 -> 8192x128),
// blocks 6144..6655 cast W0,W1 f32->bf16.
__global__ __launch_bounds__(256) void prep_kernel(const float* __restrict__ points2,
                                                   u16* __restrict__ p2T,
                                                   const float* __restrict__ points1,
                                                   u16* __restrict__ p1T,
                                                   const float* __restrict__ W0f,
                                                   u16* __restrict__ W0b,
                                                   const float* __restrict__ W1f,
                                                   u16* __restrict__ W1b) {
    __shared__ float tile[32][33];
    int id = blockIdx.x;
    int t  = threadIdx.x;
    if (id < 6144) {
        const float* in; u16* out; int R, C, b, c0, r0;
        if (id < 2048) {
            in = points2; out = p2T; R = C2; C = MM;
            b = id >> 9; int rem = id & 511;
            c0 = (rem & 63) * 32; r0 = (rem >> 6) * 32;
        } else {
            int id2 = id - 2048;
            in = points1; out = p1T; R = C1; C = NN;
            b = id2 >> 10; int rem = id2 & 1023;
            c0 = (rem & 255) * 32; r0 = (rem >> 8) * 32;
        }
        int tx = t & 31, ty = t >> 5;        // (32,8)
        const float* pin = in + (size_t)b * R * C;
        u16* pout = out + (size_t)b * R * C;
#pragma unroll
        for (int j = 0; j < 4; ++j) {
            int r = ty + j * 8;
            tile[r][tx] = pin[(size_t)(r0 + r) * C + (c0 + tx)];
        }
        __syncthreads();
#pragma unroll
        for (int j = 0; j < 4; ++j) {
            int c = ty + j * 8;
            pout[(size_t)(c0 + c) * R + (r0 + tx)] = f2bf(tile[tx][c]);
        }
    } else {
        int i = (id - 6144) * 256 + t;
        if (i < O0 * CH0) W0b[i] = f2bf(W0f[i]);
        else {
            int i2 = i - O0 * CH0;
            if (i2 < O1 * O0) W1b[i2] = f2bf(W1f[i2]);
        }
    }
}

// ---------------------------------------------------------------------------
// K2: 3-NN + combined (distance * normal) interpolation weights. f32 inputs.
// VALU-bound at ~70% issue (~20 inst/point: contract-off distance + sorted
// top-3 insert with exact top_k tie semantics; 64-lane exec-OR makes the
// insert body effectively unconditional). Near its instruction floor.
__global__ __launch_bounds__(256) void three_nn_kernel(const float* __restrict__ xyz1,
                                                       const float* __restrict__ xyz2,
                                                       const float* __restrict__ norm1,
                                                       const float* __restrict__ norm2,
                                                       int* __restrict__ idxOut,
                                                       float* __restrict__ wOut) {
#pragma clang fp contract(off)
    constexpr int CH = 1024;             // points per LDS chunk
    __shared__ float4 pts[CH];
    int b    = blockIdx.x >> 8;          // 256 blocks of 32 queries per batch
    int nblk = blockIdx.x & 255;
    int t    = threadIdx.x;
    int j    = t & 7;                    // lane within the 8-thread query group

    int n = nblk * 32 + (t >> 3);
    const float* x1 = xyz1 + (size_t)b * 3 * NN;
    float qx = x1[n], qy = x1[NN + n], qz = x1[2 * NN + n];
    float qq = (qx * qx + qy * qy) + qz * qz;

    const float* x2 = xyz2 + (size_t)b * 3 * MM;

    float d0 = 3.4e38f, d1 = 3.4e38f, d2v = 3.4e38f;
    int   i0 = 0, i1 = 0, i2 = 0;

    for (int chunk = 0; chunk < MM / CH; ++chunk) {
        __syncthreads();                 // prior scan done before overwrite
        for (int i = t; i < CH; i += 256) {
            int m = chunk * CH + i;
            float px = x2[m];
            float py = x2[MM + m];
            float pz = x2[2 * MM + m];
            float pp = (px * px + py * py) + pz * pz;
            pts[i] = make_float4(px, py, pz, pp);
        }
        __syncthreads();

#pragma unroll 8
        for (int s = 0; s < CH / 8; ++s) {
            int ml = s * 8 + j;          // ascending per thread -> stable ties
            float4 P = pts[ml];
            float qp = (qx * P.x + qy * P.y) + qz * P.z;
            float d  = (qq + P.w) - 2.0f * qp;
            if (d < d2v) {
                int m = chunk * CH + ml;
                if (d < d1) {
                    if (d < d0) { d2v = d1; i2 = i1; d1 = d0; i1 = i0; d0 = d; i0 = m; }
                    else        { d2v = d1; i2 = i1; d1 = d;  i1 = m; }
                } else          { d2v = d;  i2 = m; }
            }
        }
    }

    // merge sorted triples across the 8 lanes of the group (lexicographic tie-break)
#pragma unroll
    for (int k = 1; k <= 4; k <<= 1) {
        float e0 = __shfl_xor(d0, k, 64), e1 = __shfl_xor(d1, k, 64), e2 = __shfl_xor(d2v, k, 64);
        int   f0 = __shfl_xor(i0, k, 64), f1 = __shfl_xor(i1, k, 64), f2 = __shfl_xor(i2, k, 64);
        float ed[3] = {e0, e1, e2}; int ef[3] = {f0, f1, f2};
#pragma unroll
        for (int e = 0; e < 3; ++e) {
            float dd = ed[e]; int ff = ef[e];
            bool b2 = (dd < d2v) || (dd == d2v && ff < i2);
            if (b2) {
                bool b1 = (dd < d1) || (dd == d1 && ff < i1);
                if (b1) {
                    d2v = d1; i2 = i1;
                    bool b0 = (dd < d0) || (dd == d0 && ff < i0);
                    if (b0) { d1 = d0; i1 = i0; d0 = dd; i0 = ff; }
                    else    { d1 = dd; i1 = ff; }
                } else { d2v = dd; i2 = ff; }
            }
        }
    }

    if (j == 0) {
        float s0 = sqrtf(fmaxf(d0, 1e-20f));
        float s1 = sqrtf(fmaxf(d1, 1e-20f));
        float s2 = sqrtf(fmaxf(d2v, 1e-20f));
        float r0 = 1.0f / fmaxf(s0, 1e-10f);
        float r1 = 1.0f / fmaxf(s1, 1e-10f);
        float r2 = 1.0f / fmaxf(s2, 1e-10f);
        float rs = (r0 + r1) + r2;
        float w0 = r0 / rs, w1 = r1 / rs, w2 = r2 / rs;

        const float* nm1 = norm1 + (size_t)b * 3 * NN;
        const float* nm2 = norm2 + (size_t)b * 3 * MM;
        float ax = nm1[n], ay = nm1[NN + n], az = nm1[2 * NN + n];
        float nd[3]; int ii[3] = {i0, i1, i2};
#pragma unroll
        for (int k = 0; k < 3; ++k) {
            int ik = ii[k];
            float dx = ax - nm2[ik];
            float dy = ay - nm2[MM + ik];
            float dz = az - nm2[2 * MM + ik];
            nd[k] = sqrtf((dx * dx + dy * dy) + dz * dz);
        }
        float m0 = 1.0f / fmaxf(nd[0], 1e-10f);
        float m1 = 1.0f / fmaxf(nd[1], 1e-10f);
        float m2 = 1.0f / fmaxf(nd[2], 1e-10f);
        float ms = (m0 + m1) + m2;

        int col = b * NN + n;
        idxOut[col * 3 + 0] = i0;
        idxOut[col * 3 + 1] = i1;
        idxOut[col * 3 + 2] = i2;
        wOut[col * 3 + 0] = w0 * (m0 / ms);
        wOut[col * 3 + 1] = w1 * (m1 / ms);
        wOut[col * 3 + 2] = w2 * (m2 / ms);
    }
}

// ---------------------------------------------------------------------------
// K3: build x^T[col][k] (bf16, K-contiguous). One wave per column.
__global__ __launch_bounds__(256) void build_xT_kernel(const int* __restrict__ idx,
                                                       const float* __restrict__ w,
                                                       const u16* __restrict__ p2T,
                                                       const u16* __restrict__ p1T,
                                                       u16* __restrict__ xT) {
    int t  = threadIdx.x;
    int l  = t & 63;
    int wv = t >> 6;
    int col = blockIdx.x * 4 + wv;
    int b = col >> 13;
    int n = col & (NN - 1);
    int i0 = idx[col * 3 + 0], i1 = idx[col * 3 + 1], i2 = idx[col * 3 + 2];
    float w0 = w[col * 3 + 0], w1 = w[col * 3 + 1], w2 = w[col * 3 + 2];
    const u16* base = p2T + (size_t)b * MM * C2;

    union { uint2 v; u16 u[4]; } a0, a1, a2, o;
    a0.v = *(const uint2*)(base + (size_t)i0 * C2 + l * 4);
    a1.v = *(const uint2*)(base + (size_t)i1 * C2 + l * 4);
    a2.v = *(const uint2*)(base + (size_t)i2 * C2 + l * 4);
#pragma unroll
    for (int e = 0; e < 4; ++e)
        o.u[e] = f2bf(w0 * bf2f(a0.u[e]) + w1 * bf2f(a1.u[e]) + w2 * bf2f(a2.u[e]));
    *(uint2*)(xT + (size_t)col * CH0 + l * 4) = o.v;

    if (l < 32) {  // points1 channels 0..127
        uint2 p = *(const uint2*)(p1T + ((size_t)b * NN + n) * C1 + l * 4);
        *(uint2*)(xT + (size_t)col * CH0 + C2 + l * 4) = p;
    }
}

// ---------------------------------------------------------------------------
// K4/K6: GEMM  C^T[col][m] = sum_k A[m][k] * Bt[col][k] + bias[m]
// 128 rows x COLT cols, BK=64, 256 threads, 16x16x32 bf16 MFMA.
// A staging: async global_load_lds (16B/lane), XOR-swizzled, double-buffered.
// B staging: DMA if !FUSEB; if FUSEB, VGPR path applying relu(f*sc+sh);
// sc/sh computed in the PROLOGUE from the 16-record reduced stats (redB) +
// g/be — replaces the separate bn_params dispatch.
// BN stats out: shuffle-reduce -> LDS atomics -> one partial record/block.
template <int KDIM, int LDC, int COLT, bool FUSEB>
__global__ __launch_bounds__(256) void gemm_bt_kernel(const u16* __restrict__ A,
                                                      const u16* __restrict__ Bt,
                                                      u16* __restrict__ Ct,
                                                      const float* __restrict__ bias,
                                                      const float* __restrict__ redB,
                                                      const float* __restrict__ gB,
                                                      const float* __restrict__ beB,
                                                      float invN,
                                                      float* __restrict__ partials) {
    constexpr int KT  = KDIM / 64;
    constexpr int NI  = COLT / 32;
    constexpr int ASZ = 128 * 64;            // u16 elements per A buffer
    constexpr int BSZ = COLT * 64;
    __shared__ u16 smem[2 * ASZ + 2 * BSZ];  // staging; overlaid by Cs+reds after loop
    __shared__ float sSc[FUSEB ? KDIM : 1];
    __shared__ float sSh[FUSEB ? KDIM : 1];

    int t   = threadIdx.x;
    int l   = t & 63;
    int wv  = t >> 6;
    int rl  = l >> 3;                    // staging row-in-group 0..7
    int cg  = ((l & 7) ^ rl) * 8;        // swizzled global chunk (elements)
    int mb0 = blockIdx.y * 128;
    int cb0 = blockIdx.x * COLT;
    int lm  = l & 15;
    int q   = l >> 4;
    int wm0 = (wv & 1) * 64;
    int wn0 = (wv >> 1) * (COLT / 2);

    const u16* Abase = A  + (size_t)mb0 * KDIM;
    const u16* Bbase = Bt + (size_t)cb0 * KDIM;

    if (FUSEB) {
        // fold reduced BN0 stats into scale/shift (KDIM == 256 == blockDim)
        int by = t >> 7, chL = t & 127;
        const float* base = redB + (size_t)by * 8 * 256;
        float s = 0.f, s2 = 0.f;
#pragma unroll
        for (int i = 0; i < 8; ++i) {
            s  += base[i * 256 + chL];
            s2 += base[i * 256 + 128 + chL];
        }
        float mean = s * invN;
        float var  = fmaxf(s2 * invN - mean * mean, 0.f);
        float inv  = rsqrtf(var + BN_EPS);
        float sc   = gB[t] * inv;
        sSc[t] = sc;
        sSh[t] = beB[t] - mean * sc;
        __syncthreads();
    }

    auto stage = [&](int buf, int k0) {
#pragma unroll
        for (int iss = 0; iss < 4; ++iss) {              // A: 128 rows, DMA
            int row = wv * 32 + iss * 8;
            const u16* g = Abase + (size_t)(row + rl) * KDIM + k0 + cg;
            __builtin_amdgcn_global_load_lds(
                (const __attribute__((address_space(1))) unsigned int*)g,
                (__attribute__((address_space(3))) unsigned int*)(&smem[buf * ASZ + row * 64]),
                16, 0, 0);
        }
        if (!FUSEB) {
#pragma unroll
            for (int iss = 0; iss < COLT / 32; ++iss) {  // B: COLT rows, DMA
                int row = wv * (COLT / 4) + iss * 8;
                const u16* g = Bbase + (size_t)(row + rl) * KDIM + k0 + cg;
                __builtin_amdgcn_global_load_lds(
                    (const __attribute__((address_space(1))) unsigned int*)g,
                    (__attribute__((address_space(3))) unsigned int*)(&smem[2 * ASZ + buf * BSZ + row * 64]),
                    16, 0, 0);
            }
        } else {
            // VGPR path with fused BN+ReLU: 64 rows x 64 k / 256 thr = 16/thread
            int row = t >> 2;                            // 0..63
            int kc  = (t & 3) * 16;
            const u16* gp = Bbase + (size_t)row * KDIM + k0 + kc;
            union { uint4 v; u16 u[8]; } lo, hi;
            lo.v = *(const uint4*)gp;
            hi.v = *(const uint4*)(gp + 8);
#pragma unroll
            for (int e = 0; e < 8; ++e) {
                float f0 = bf2f(lo.u[e]);
                lo.u[e] = f2bf(fmaxf(f0 * sSc[k0 + kc + e] + sSh[k0 + kc + e], 0.f));
                float f1 = bf2f(hi.u[e]);
                hi.u[e] = f2bf(fmaxf(f1 * sSc[k0 + kc + 8 + e] + sSh[k0 + kc + 8 + e], 0.f));
            }
            int c0 = kc >> 3;                            // chunk index of lo
            u16* dstB = &smem[2 * ASZ + buf * BSZ + row * 64];
            *(uint4*)&dstB[((c0)     ^ (row & 7)) * 8] = lo.v;
            *(uint4*)&dstB[((c0 + 1) ^ (row & 7)) * 8] = hi.v;
        }
    };

    f32x4 acc[4][NI] = {};

    stage(0, 0);
    for (int kt = 0; kt < KT; ++kt) {
        __syncthreads();                                  // drains DMA + ds_writes
        if (kt + 1 < KT) stage((kt + 1) & 1, (kt + 1) * 64);
        const u16* As = &smem[(kt & 1) * ASZ];
        const u16* Bs = &smem[2 * ASZ + (kt & 1) * BSZ];
#pragma unroll
        for (int ks = 0; ks < 2; ++ks) {
            int csw = ((ks * 4 + q) ^ (lm & 7)) * 8;      // un-swizzle chunk offset
            short8 av[4], bv[NI];
#pragma unroll
            for (int mi = 0; mi < 4; ++mi)
                av[mi] = *(const short8*)&As[(wm0 + mi * 16 + lm) * 64 + csw];
#pragma unroll
            for (int ni = 0; ni < NI; ++ni)
                bv[ni] = *(const short8*)&Bs[(wn0 + ni * 16 + lm) * 64 + csw];
#pragma unroll
            for (int mi = 0; mi < 4; ++mi)
#pragma unroll
                for (int ni = 0; ni < NI; ++ni)
                    acc[mi][ni] = __builtin_amdgcn_mfma_f32_16x16x32_bf16(
                        av[mi], bv[ni], acc[mi][ni], 0, 0, 0);
        }
    }

    // ---- Epilogue (LDS overlay): Cs = COLT x 136 u16, reds = 256 floats ----
    u16*   Cs   = smem;                              // [colL*136 + m]
    float* reds = (float*)&smem[COLT * 136];         // [s*128 + chL]

    __syncthreads();                                  // all MFMA LDS reads done
    if (t < 256) reds[t] = 0.f;
    __syncthreads();

#pragma unroll
    for (int mi = 0; mi < 4; ++mi) {
        int chL = wm0 + mi * 16 + q * 4;             // local channel, 4 consecutive
        float bv4[4];
#pragma unroll
        for (int r = 0; r < 4; ++r) bv4[r] = bias[mb0 + chL + r];
        float s[4]  = {0.f, 0.f, 0.f, 0.f};
        float s2[4] = {0.f, 0.f, 0.f, 0.f};
#pragma unroll
        for (int ni = 0; ni < NI; ++ni) {
            int colL = wn0 + ni * 16 + lm;
            union { u16 u[4]; uint2 d; } pk;
#pragma unroll
            for (int r = 0; r < 4; ++r) {
                float v = acc[mi][ni][r] + bv4[r];
                s[r]  += v;
                s2[r] += v * v;
                pk.u[r] = f2bf(v);
            }
            *(uint2*)&Cs[colL * 136 + chL] = pk.d;
        }
#pragma unroll
        for (int r = 0; r < 4; ++r) {
            float a = s[r], b2 = s2[r];
#pragma unroll
            for (int off = 1; off < 16; off <<= 1) {
                a  += __shfl_xor(a, off, 64);
                b2 += __shfl_xor(b2, off, 64);
            }
            if (lm == 0) {
                atomicAdd(&reds[chL + r], a);          // LDS atomic (on-CU)
                atomicAdd(&reds[128 + chL + r], b2);
            }
        }
    }
    __syncthreads();

    // coalesced C-store: COLT rows x 128 m; each half-row = 64 u16 = 8 x uint4
    for (int u = t; u < COLT * 2; u += 256) {
        int c = u >> 1, h = u & 1;
        const u16* src = &Cs[c * 136 + h * 64];
        u16* dst = Ct + (size_t)(cb0 + c) * LDC + mb0 + h * 64;
#pragma unroll
        for (int jj = 0; jj < 8; ++jj)
            *(uint4*)(dst + jj * 8) = *(const uint4*)(src + jj * 8);
    }
    // one plain partial record per block
    partials[((size_t)blockIdx.y * gridDim.x + blockIdx.x) * 256 + t] = reds[t];
}

// ---------------------------------------------------------------------------
// K5a: stage-1 partial reduction: 16 blocks, block r sums `chunk` records.
__global__ __launch_bounds__(256) void reduce_partials_kernel(const float* __restrict__ in,
                                                              float* __restrict__ out,
                                                              int chunk) {
    int t = threadIdx.x, r = blockIdx.x;
    const float* base = in + (size_t)r * chunk * 256;
    float s = 0.f;
#pragma unroll 8
    for (int i = 0; i < chunk; ++i) s += base[(size_t)i * 256 + t];
    out[(size_t)r * 256 + t] = s;
}

// ---------------------------------------------------------------------------
// K8: final BN+ReLU on y1^T[col][c] (bf16) and transpose to out[b][c][n] (f32).
// Prologue folds red1 (16 records) + g1/be1 into scale/shift in LDS.
__global__ __launch_bounds__(256) void finalize_kernel(const u16* __restrict__ y1T,
                                                       const float* __restrict__ red1,
                                                       const float* __restrict__ g1,
                                                       const float* __restrict__ be1,
                                                       float invN,
                                                       float* __restrict__ out) {
    __shared__ float tile[64][129];
    __shared__ float sc[O1], sh[O1];
    int t  = threadIdx.x;
    int b  = blockIdx.y;
    int n0 = blockIdx.x * 64;

    if (t < O1) {
        float s = 0.f, s2 = 0.f;
#pragma unroll
        for (int i = 0; i < 16; ++i) {
            s  += red1[i * 256 + t];
            s2 += red1[i * 256 + 128 + t];
        }
        float mean = s * invN;
        float var  = fmaxf(s2 * invN - mean * mean, 0.f);
        float inv  = rsqrtf(var + BN_EPS);
        float scv  = g1[t] * inv;
        sc[t] = scv;
        sh[t] = be1[t] - mean * scv;
    }
    __syncthreads();

#pragma unroll
    for (int it = 0; it < 32; ++it) {
        int flat = it * 256 + t;
        int cl = flat >> 7;          // local col 0..63
        int c  = flat & 127;
        int col = b * NN + n0 + cl;
        float v = bf2f(y1T[(size_t)col * O1 + c]);
        tile[cl][c] = fmaxf(v * sc[c] + sh[c], 0.f);
    }
    __syncthreads();
#pragma unroll
    for (int it = 0; it < 32; ++it) {
        int flat = it * 256 + t;
        int c  = flat >> 6;          // channel 0..127
        int nl = flat & 63;
        out[(size_t)b * O1 * NN + (size_t)c * NN + n0 + nl] = tile[nl][c];
    }
}

// ---------------------------------------------------------------------------
extern "C" void kernel_launch(void* const* d_in, const int* in_sizes, int n_in,
                              void* d_out, int out_size, void* d_ws, size_t ws_size,
                              hipStream_t stream) {
    (void)in_sizes; (void)n_in; (void)out_size; (void)ws_size;

    const float* xyz1    = (const float*)d_in[0];
    const float* xyz2    = (const float*)d_in[1];
    const float* norm1   = (const float*)d_in[2];
    const float* norm2   = (const float*)d_in[3];
    const float* points1 = (const float*)d_in[4];
    const float* points2 = (const float*)d_in[5];
    const float* W0f     = (const float*)d_in[6];
    const float* b0      = (const float*)d_in[7];
    const float* g0      = (const float*)d_in[8];
    const float* be0     = (const float*)d_in[9];
    const float* W1f     = (const float*)d_in[10];
    const float* b1      = (const float*)d_in[11];
    const float* g1      = (const float*)d_in[12];
    const float* be1     = (const float*)d_in[13];
    float* out = (float*)d_out;

    // workspace carve-up (all 256B-aligned)
    char* w8 = (char*)d_ws;
    size_t off = 0;
    auto carve = [&](size_t bytes) { void* p = w8 + off; off += (bytes + 255) & ~(size_t)255; return p; };
    int*   idxW   = (int*)  carve((size_t)NCOL * 3 * sizeof(int));
    float* wW     = (float*)carve((size_t)NCOL * 3 * sizeof(float));
    u16*   p2T    = (u16*)  carve((size_t)BB * MM * C2 * 2);
    u16*   p1T    = (u16*)  carve((size_t)BB * NN * C1 * 2);
    u16*   W0b    = (u16*)  carve((size_t)O0 * CH0 * 2);
    u16*   W1b    = (u16*)  carve((size_t)O1 * O0 * 2);
    u16*   xT     = (u16*)  carve((size_t)NCOL * CH0 * 2);
    u16*   y0T    = (u16*)  carve((size_t)NCOL * O0 * 2);
    u16*   y1T    = (u16*)  carve((size_t)NCOL * O1 * 2);
    float* part0  = (float*)carve((size_t)1024 * 256 * sizeof(float)); // 1024 records
    float* part1  = (float*)carve((size_t)512 * 256 * sizeof(float));  // 512 records
    float* red0   = (float*)carve((size_t)16 * 256 * sizeof(float));
    float* red1   = (float*)carve((size_t)16 * 256 * sizeof(float));

    const float invN = 1.0f / (float)NCOL;

    prep_kernel<<<6656, 256, 0, stream>>>(points2, p2T, points1, p1T,
                                          W0f, W0b, W1f, W1b);

    three_nn_kernel<<<BB * (NN / 32), 256, 0, stream>>>(xyz1, xyz2, norm1, norm2, idxW, wW);

    build_xT_kernel<<<NCOL / 4, 256, 0, stream>>>(idxW, wW, p2T, p1T, xT);

    // GEMM0: 512 x-blocks x 2 y-halves = 1024 blocks, COLT=64
    gemm_bt_kernel<CH0, O0, 64, false><<<dim3(NCOL / 64, O0 / 128), 256, 0, stream>>>(
        W0b, xT, y0T, b0, nullptr, nullptr, nullptr, invN, part0);
    reduce_partials_kernel<<<16, 256, 0, stream>>>(part0, red0, 64);

    // GEMM1: fused BN0+ReLU on B; prologue folds red0+g0/be0 into scale/shift
    gemm_bt_kernel<O0, O1, 64, true><<<dim3(NCOL / 64, O1 / 128), 256, 0, stream>>>(
        W1b, y0T, y1T, b1, red0, g0, be0, invN, part1);
    reduce_partials_kernel<<<16, 256, 0, stream>>>(part1, red1, 32);

    finalize_kernel<<<dim3(NN / 64, BB), 256, 0, stream>>>(y1T, red1, g1, be1, invN, out);
}